// Round 10
// baseline (292.250 us; speedup 1.0000x reference)
//
#include <hip/hip_runtime.h>

#define B 4
#define S 2048
#define H 16
#define D 64
#define E 1024
#define BH (B*H)

typedef __bf16 bf16;
typedef __bf16 bf16x8 __attribute__((ext_vector_type(8)));
typedef __bf16 bf16x4 __attribute__((ext_vector_type(4)));
typedef __bf16 bf16x2 __attribute__((ext_vector_type(2)));
typedef float  f32x4  __attribute__((ext_vector_type(4)));
typedef float  f32x16 __attribute__((ext_vector_type(16)));
typedef unsigned int u32;

__device__ __forceinline__ f32x4 mfma16(bf16x8 a, bf16x8 b, f32x4 c) {
    return __builtin_amdgcn_mfma_f32_16x16x32_bf16(a, b, c, 0, 0, 0);
}
__device__ __forceinline__ f32x16 mfma32(bf16x8 a, bf16x8 b, f32x16 c) {
    return __builtin_amdgcn_mfma_f32_32x32x16_bf16(a, b, c, 0, 0, 0);
}

__device__ __forceinline__ unsigned pack2(float lo, float hi) {
    union { bf16x2 v; unsigned u; } x;
    x.v[0] = (bf16)lo; x.v[1] = (bf16)hi;
    return x.u;
}
__device__ __forceinline__ bf16x8 frag4(unsigned a0, unsigned a1, unsigned a2, unsigned a3) {
    union { unsigned u[4]; bf16x8 v; } x;
    x.u[0] = a0; x.u[1] = a1; x.u[2] = a2; x.u[3] = a3;
    return x.v;
}
// async global->LDS DMA, 16B per lane. LDS dest must be wave-uniform base;
// HW writes lane l at dest + l*16. Global src IS per-lane (swizzle goes there).
__device__ __forceinline__ void async_copy16(const bf16* g, bf16* l) {
    __builtin_amdgcn_global_load_lds(
        (const __attribute__((address_space(1))) u32*)g,
        (__attribute__((address_space(3))) u32*)l, 16, 0, 0);
}

#define SCALE 0.04508422002778f   // (1/sqrt(1024)) * log2(e), folded into Q

// ---------------------------------------------------------------------------
// Kernel 1: QKV projection + fused Wo fp32->bf16 (type 3). UNCHANGED.
// ---------------------------------------------------------------------------
__global__ __launch_bounds__(256) void proj_kernel(
    const float* __restrict__ values, const float* __restrict__ keys,
    const float* __restrict__ query,  const float* __restrict__ Wv,
    const float* __restrict__ Wk,     const float* __restrict__ Wq,
    const float* __restrict__ Wo,
    bf16* __restrict__ qp, bf16* __restrict__ kp, bf16* __restrict__ vt,
    bf16* __restrict__ wb)
{
    const int t    = threadIdx.x;
    const int bh   = blockIdx.y;
    const int type = blockIdx.z;

    if (type == 3) {
        int idx = (bh * 16 + blockIdx.x) * 1024 + t * 4;
        f32x4 v = *(const f32x4*)(Wo + idx);
        *(bf16x4*)(wb + idx) = __builtin_convertvector(v, bf16x4);
        return;
    }

    const int b = bh >> 4, h = bh & 15;
    const int s0 = blockIdx.x * 128;
    const int w = t >> 6, lane = t & 63;
    const int m = lane & 15, g = lane >> 4;
    const int row0 = s0 + w * 32;

    const float* X = (type == 0) ? query : (type == 1) ? keys : values;
    const float* W = (type == 0) ? Wq    : (type == 1) ? Wk   : Wv;

    __shared__ bf16 Xs[128 * 72];   // staged X tile, bf16, padded stride

    // coalesced staging: 8 rounds x 256 thr x 16B fp32 = 32KB tile
    #pragma unroll
    for (int p = 0; p < 8; ++p) {
        int id = p * 256 + t;
        int row = id >> 4, cq = (id & 15) * 4;
        f32x4 v = *(const f32x4*)(X + (size_t)(b * S + s0 + row) * E + h * D + cq);
        if (type == 0) v *= SCALE;
        *(bf16x4*)(Xs + row * 72 + cq) = __builtin_convertvector(v, bf16x4);
    }

    bf16x8 wf[4][2];
    #pragma unroll
    for (int nt = 0; nt < 4; ++nt)
        #pragma unroll
        for (int kb = 0; kb < 2; ++kb) {
            const float* pw = W + (nt * 16 + m) * 64 + kb * 32 + g * 8;
            f32x4 lo = *(const f32x4*)pw;
            f32x4 hi = *(const f32x4*)(pw + 4);
            bf16x8 f;
            #pragma unroll
            for (int i = 0; i < 4; ++i) { f[i] = (bf16)lo[i]; f[4 + i] = (bf16)hi[i]; }
            wf[nt][kb] = f;
        }

    __syncthreads();

    bf16x8 xa[2][2];
    #pragma unroll
    for (int mt = 0; mt < 2; ++mt)
        #pragma unroll
        for (int kb = 0; kb < 2; ++kb)
            xa[mt][kb] = *(const bf16x8*)(Xs + (w * 32 + mt * 16 + m) * 72 + kb * 32 + g * 8);

    if (type == 2) {
        #pragma unroll
        for (int mt = 0; mt < 2; ++mt)
            #pragma unroll
            for (int nt = 0; nt < 4; ++nt) {
                f32x4 acc = (f32x4){0.f, 0.f, 0.f, 0.f};
                acc = mfma16(xa[mt][0], wf[nt][0], acc);
                acc = mfma16(xa[mt][1], wf[nt][1], acc);
                bf16x4 pk = __builtin_convertvector(acc, bf16x4);
                *(bf16x4*)(vt + (size_t)(bh * D + nt * 16 + m) * S + row0 + mt * 16 + g * 4) = pk;
            }
    } else {
        bf16* out = (type == 0) ? qp : kp;
        #pragma unroll
        for (int mt = 0; mt < 2; ++mt)
            #pragma unroll
            for (int nt = 0; nt < 4; ++nt) {
                f32x4 acc = (f32x4){0.f, 0.f, 0.f, 0.f};
                acc = mfma16(wf[nt][0], xa[mt][0], acc);
                acc = mfma16(wf[nt][1], xa[mt][1], acc);
                bf16x4 pk = __builtin_convertvector(acc, bf16x4);
                *(bf16x4*)(out + (size_t)(bh * S + row0 + mt * 16 + m) * D + nt * 16 + g * 4) = pk;
            }
    }
}

// ---------------------------------------------------------------------------
// Kernel 2: flash attention — R12: R9 body, parameterized into 2-pass form.
// DIAGNOSTIC ROUND: the "rest" (total - attn ~ 180us) has been invariant
// across 3 different proj/out_gemm implementations; proj/out_gemm never
// appear in top-5 because every attn dispatch (~89us) outranks them.
// Splitting attn into two ~47us KV-half passes (f32 partial O/L, exact
// combine — static softmax needs no max rescale) lets anything >50us
// surface WITH counters. mode: 0 = single-pass (== R9, ws fallback),
// 1 = store partials (kt [0,16)), 2 = combine + final (kt [16,32)).
// ---------------------------------------------------------------------------
__global__ __launch_bounds__(256, 2) void attn_kernel(
    const bf16* __restrict__ qp, const bf16* __restrict__ kp,
    const bf16* __restrict__ vt, bf16* __restrict__ attn,
    float* __restrict__ Opart, float* __restrict__ Lpart,
    int k0, int k1, int mode)
{
    const int t  = threadIdx.x;
    const int bh = blockIdx.x;
    const int b  = bh >> 4, h = bh & 15;
    const int q0 = blockIdx.y * 256;
    const int w  = t >> 6, lane = t & 63;
    const int l31 = lane & 31, h5 = lane >> 5;

    __shared__ bf16 Ks[2][64 * 64];   // [buf][row*64 + col], swizzled slots
    __shared__ bf16 Vs[2][64 * 64];

    // Q fragments: B operand, 2 q-blocks x 4 d-kblocks (held all kernel)
    bf16x8 qa[2][4];
    #pragma unroll
    for (int qb = 0; qb < 2; ++qb)
        #pragma unroll
        for (int kb = 0; kb < 4; ++kb)
            qa[qb][kb] = *(const bf16x8*)(qp + (size_t)(bh * S + q0 + w * 64 + qb * 32 + l31) * D + kb * 16 + h5 * 8);

    f32x16 O[2][2];                // [qb][db]
    #pragma unroll
    for (int qb = 0; qb < 2; ++qb)
        #pragma unroll
        for (int db = 0; db < 2; ++db)
            #pragma unroll
            for (int i = 0; i < 16; ++i) O[qb][db][i] = 0.f;
    float Lacc[2] = {0.f, 0.f};

    // staging geometry: 2 rounds x 256 thr x 16B = 8KB tile; per-lane source
    // row = p*32 + w*8 + (lane>>3); slot = (lane&7) ^ ((lane>>3)&7)
    const int srow  = lane >> 3;
    const int sslot = (lane & 7) ^ srow;
    const bf16* ks0 = kp + ((size_t)bh * S + w * 8 + srow) * D + sslot * 8;
    const bf16* vs0 = vt + ((size_t)bh * D + w * 8 + srow) * S + sslot * 8;
    const int swz = (l31 & 7);            // read-side XOR (row&7 == l31&7)

    // prologue: stage kt=k0 into buf 0
    #pragma unroll
    for (int p = 0; p < 2; ++p) {
        async_copy16(ks0 + (size_t)(k0 * 64 + p * 32) * D, &Ks[0][p * 2048 + w * 512]);
        async_copy16(vs0 + (size_t)(p * 32) * S + k0 * 64, &Vs[0][p * 2048 + w * 512]);
    }
    __syncthreads();

    int cur = 0;
    for (int kt = k0; kt < k1; ++kt) {
        if (kt + 1 < k1) {
            #pragma unroll
            for (int p = 0; p < 2; ++p) {
                async_copy16(ks0 + (size_t)((kt + 1) * 64 + p * 32) * D,
                             &Ks[cur ^ 1][p * 2048 + w * 512]);
                async_copy16(vs0 + (size_t)(p * 32) * S + (kt + 1) * 64,
                             &Vs[cur ^ 1][p * 2048 + w * 512]);
            }
        }
        const bf16* KsB = Ks[cur];
        const bf16* VsB = Vs[cur];

        #pragma unroll
        for (int kg = 0; kg < 2; ++kg) {
            bf16x8 kf[4];
            #pragma unroll
            for (int kb = 0; kb < 4; ++kb)
                kf[kb] = *(const bf16x8*)&KsB[(kg * 32 + l31) * 64 + (((kb * 2 + h5) ^ swz) << 3)];
            bf16x8 vf[2][2];   // [kap][db]
            #pragma unroll
            for (int kap = 0; kap < 2; ++kap)
                #pragma unroll
                for (int db = 0; db < 2; ++db)
                    vf[kap][db] = *(const bf16x8*)&VsB[(db * 32 + l31) * 64 + (((kg * 4 + kap * 2 + h5) ^ swz) << 3)];

            // ---- QK: E^T[key-slot][q] for 32 keys x 64 q ----
            f32x16 e[2];
            #pragma unroll
            for (int qb = 0; qb < 2; ++qb)
                #pragma unroll
                for (int i = 0; i < 16; ++i) e[qb][i] = 0.f;
            #pragma unroll
            for (int kb = 0; kb < 4; ++kb) {
                e[0] = mfma32(kf[kb], qa[0][kb], e[0]);
                e[1] = mfma32(kf[kb], qa[1][kb], e[1]);
            }

            // ---- exp2, pack, packed 4-shfl exchange (R5-derived), PV ----
            #pragma unroll
            for (int qb = 0; qb < 2; ++qb) {
                unsigned own[8];
                float ls = 0.f;
                #pragma unroll
                for (int c = 0; c < 8; ++c) {
                    float lo = __builtin_amdgcn_exp2f(e[qb][2 * c]);
                    float hi = __builtin_amdgcn_exp2f(e[qb][2 * c + 1]);
                    ls += lo + hi;
                    own[c] = pack2(lo, hi);
                }
                Lacc[qb] += ls;
                // packed exchange: one shfl serves both halves.
                unsigned x0 = __shfl_xor(h5 ? own[0] : own[2], 32, 64);
                unsigned x1 = __shfl_xor(h5 ? own[1] : own[3], 32, 64);
                unsigned x4 = __shfl_xor(h5 ? own[4] : own[6], 32, 64);
                unsigned x5 = __shfl_xor(h5 ? own[5] : own[7], 32, 64);
                {   // kap = 0
                    unsigned a0 = h5 ? x0 : own[0];
                    unsigned a1 = h5 ? x1 : own[1];
                    unsigned a2 = h5 ? own[2] : x0;
                    unsigned a3 = h5 ? own[3] : x1;
                    bf16x8 pf = frag4(a0, a1, a2, a3);
                    O[qb][0] = mfma32(pf, vf[0][0], O[qb][0]);
                    O[qb][1] = mfma32(pf, vf[0][1], O[qb][1]);
                }
                {   // kap = 1
                    unsigned a0 = h5 ? x4 : own[4];
                    unsigned a1 = h5 ? x5 : own[5];
                    unsigned a2 = h5 ? own[6] : x4;
                    unsigned a3 = h5 ? own[7] : x5;
                    bf16x8 pf = frag4(a0, a1, a2, a3);
                    O[qb][0] = mfma32(pf, vf[1][0], O[qb][0]);
                    O[qb][1] = mfma32(pf, vf[1][1], O[qb][1]);
                }
            }
        }
        __syncthreads();   // drains vmcnt: next tile's DMA complete; all waves done with cur
        cur ^= 1;
    }

    // ---- epilogue ----
    if (mode == 1) {
        // pass 1: store partial O (f32, coalesced 128B runs) and L
        #pragma unroll
        for (int qb = 0; qb < 2; ++qb) {
            float Ls = Lacc[qb] + __shfl_xor(Lacc[qb], 32, 64);
            int qq = q0 + w * 64 + qb * 32 + l31;
            if (h5 == 0) Lpart[(size_t)bh * S + qq] = Ls;
            #pragma unroll
            for (int r = 0; r < 16; ++r) {
                int crow = (r & 3) + 8 * (r >> 2) + 4 * h5;
                int qg = q0 + w * 64 + qb * 32 + crow;
                #pragma unroll
                for (int db = 0; db < 2; ++db)
                    Opart[((size_t)bh * S + qg) * D + db * 32 + l31] = O[qb][db][r];
            }
        }
    } else {
        // mode 0: normalize own sums; mode 2: combine with pass-1 partials
        #pragma unroll
        for (int qb = 0; qb < 2; ++qb) {
            float Ls = Lacc[qb] + __shfl_xor(Lacc[qb], 32, 64);
            if (mode == 2) Ls += Lpart[(size_t)bh * S + q0 + w * 64 + qb * 32 + l31];
            float li = 1.f / Ls;
            #pragma unroll
            for (int r = 0; r < 16; ++r) {
                int crow = (r & 3) + 8 * (r >> 2) + 4 * h5;
                float lr = __shfl(li, crow | (lane & 32), 64);
                int qg = q0 + w * 64 + qb * 32 + crow;
                #pragma unroll
                for (int db = 0; db < 2; ++db) {
                    float o = O[qb][db][r];
                    if (mode == 2)
                        o += Opart[((size_t)bh * S + qg) * D + db * 32 + l31];
                    attn[(size_t)(b * S + qg) * E + h * D + db * 32 + l31] = (bf16)(o * lr);
                }
            }
        }
    }
}

// ---------------------------------------------------------------------------
// Kernel 3: out = attn @ Wo^T + bo. UNCHANGED from R11.
// ---------------------------------------------------------------------------
__global__ __launch_bounds__(256, 4) void out_gemm(
    const bf16* __restrict__ A, const bf16* __restrict__ wo,
    const float* __restrict__ bo, float* __restrict__ out)
{
    const int t  = threadIdx.x;
    const int n0 = blockIdx.x * 64;
    const int m0 = blockIdx.y * 128;
    const int w  = t >> 6, lane = t & 63;
    const int l31 = lane & 31, h5 = lane >> 5;
    const int wm = w >> 1, wn = w & 1;   // 2x2 waves over 128m x 64n

    __shared__ bf16 As[128 * 64];   // [m][k-slot], swizzled slots, 16KB
    __shared__ bf16 Bs[64 * 64];    // [n][k-slot], 8KB

    f32x16 acc[2];                  // [mi] : wave tile 64m x 32n
    #pragma unroll
    for (int mi = 0; mi < 2; ++mi)
        #pragma unroll
        for (int i = 0; i < 16; ++i) acc[mi][i] = 0.f;

    // staging source (swizzled): lane -> row = base + (lane>>3), slot = (lane&7)^(lane>>3)
    const int srow  = lane >> 3;
    const int sslot = (lane & 7) ^ srow;
    const bf16* asrc = A  + ((size_t)(m0 + w * 8 + srow)) * E + sslot * 8;
    const bf16* bsrc = wo + ((size_t)(n0 + w * 8 + srow)) * E + sslot * 8;
    const int swz = (l31 & 7);      // read-side XOR (row&7 == l31&7)

    for (int kt = 0; kt < E / 64; ++kt) {
        if (kt) __syncthreads();    // all waves done reading previous tile
        // DMA this K-slab: A 128x64 (4 rounds), B 64x64 (2 rounds)
        #pragma unroll
        for (int p = 0; p < 4; ++p)
            async_copy16(asrc + (size_t)(p * 32) * E + kt * 64, &As[(p * 32 + w * 8) * 64]);
        #pragma unroll
        for (int p = 0; p < 2; ++p)
            async_copy16(bsrc + (size_t)(p * 32) * E + kt * 64, &Bs[(p * 32 + w * 8) * 64]);
        __syncthreads();            // vmcnt drained -> tile ready

        #pragma unroll
        for (int ks = 0; ks < 4; ++ks) {
            bf16x8 bf = *(const bf16x8*)&Bs[(wn * 32 + l31) * 64 + (((ks * 2 + h5) ^ swz) << 3)];
            #pragma unroll
            for (int mi = 0; mi < 2; ++mi) {
                bf16x8 af = *(const bf16x8*)&As[(wm * 64 + mi * 32 + l31) * 64 + (((ks * 2 + h5) ^ swz) << 3)];
                acc[mi] = mfma32(af, bf, acc[mi]);
            }
        }
    }

    // epilogue: D col = l31 (n), row = (r&3)+8*(r>>2)+4*h5 (m); bias along n
    const float bias = bo[n0 + wn * 32 + l31];
    #pragma unroll
    for (int mi = 0; mi < 2; ++mi)
        #pragma unroll
        for (int r = 0; r < 16; ++r) {
            int crow = (r & 3) + 8 * (r >> 2) + 4 * h5;
            out[(size_t)(m0 + wm * 64 + mi * 32 + crow) * E + n0 + wn * 32 + l31] =
                acc[mi][r] + bias;
        }
}

// ---------------------------------------------------------------------------
extern "C" void kernel_launch(void* const* d_in, const int* in_sizes, int n_in,
                              void* d_out, int out_size, void* d_ws, size_t ws_size,
                              hipStream_t stream) {
    const float* values = (const float*)d_in[0];
    const float* keys   = (const float*)d_in[1];
    const float* query  = (const float*)d_in[2];
    const float* Wv     = (const float*)d_in[3];
    const float* Wk     = (const float*)d_in[4];
    const float* Wq     = (const float*)d_in[5];
    const float* Wo     = (const float*)d_in[6];
    const float* bo     = (const float*)d_in[7];
    float* out = (float*)d_out;

    bf16* qp   = (bf16*)d_ws;
    bf16* kp   = qp  + (size_t)BH * S * D;
    bf16* vt   = kp  + (size_t)BH * S * D;
    bf16* attn = vt  + (size_t)BH * S * D;
    bf16* wb   = attn + (size_t)BH * S * D;   // 2 MB for bf16 Wo

    const size_t base   = (size_t)BH * S * D * 2 * 4 + (size_t)E * E * 2;  // 69.2 MB
    float* Opart = (float*)((char*)d_ws + base);
    float* Lpart = (float*)((char*)d_ws + base + (size_t)BH * S * D * 4);
    const size_t needed = base + (size_t)BH * S * D * 4 + (size_t)BH * S * 4;  // 103.3 MB

    proj_kernel<<<dim3(S / 128, BH, 4), 256, 0, stream>>>(
        values, keys, query, Wv, Wk, Wq, Wo, qp, kp, vt, wb);

    if (ws_size >= needed) {
        // two-pass: pass 1 kt [0,16) stores partials; pass 2 kt [16,32) combines
        attn_kernel<<<dim3(BH, S / 256), 256, 0, stream>>>(
            qp, kp, vt, attn, Opart, Lpart, 0, 16, 1);
        attn_kernel<<<dim3(BH, S / 256), 256, 0, stream>>>(
            qp, kp, vt, attn, Opart, Lpart, 16, 32, 2);
    } else {
        // fallback: single pass, identical to R9 behavior
        attn_kernel<<<dim3(BH, S / 256), 256, 0, stream>>>(
            qp, kp, vt, attn, Opart, Lpart, 0, 32, 0);
    }

    out_gemm<<<dim3(E / 64, (B * S) / 128), 256, 0, stream>>>(attn, wb, bo, out);
}

// Round 12
// 272.436 us; speedup vs baseline: 1.0727x; 1.0727x over previous
//
#include <hip/hip_runtime.h>

#define B 4
#define S 2048
#define H 16
#define D 64
#define E 1024
#define BH (B*H)

typedef __bf16 bf16;
typedef __bf16 bf16x8 __attribute__((ext_vector_type(8)));
typedef __bf16 bf16x4 __attribute__((ext_vector_type(4)));
typedef __bf16 bf16x2 __attribute__((ext_vector_type(2)));
typedef float  f32x4  __attribute__((ext_vector_type(4)));
typedef float  f32x16 __attribute__((ext_vector_type(16)));
typedef unsigned int u32;

__device__ __forceinline__ f32x4 mfma16(bf16x8 a, bf16x8 b, f32x4 c) {
    return __builtin_amdgcn_mfma_f32_16x16x32_bf16(a, b, c, 0, 0, 0);
}
__device__ __forceinline__ f32x16 mfma32(bf16x8 a, bf16x8 b, f32x16 c) {
    return __builtin_amdgcn_mfma_f32_32x32x16_bf16(a, b, c, 0, 0, 0);
}

__device__ __forceinline__ unsigned pack2(float lo, float hi) {
    union { bf16x2 v; unsigned u; } x;
    x.v[0] = (bf16)lo; x.v[1] = (bf16)hi;
    return x.u;
}
__device__ __forceinline__ bf16x8 frag4(unsigned a0, unsigned a1, unsigned a2, unsigned a3) {
    union { unsigned u[4]; bf16x8 v; } x;
    x.u[0] = a0; x.u[1] = a1; x.u[2] = a2; x.u[3] = a3;
    return x.v;
}
// async global->LDS DMA, 16B per lane. LDS dest must be wave-uniform base;
// HW writes lane l at dest + l*16. Global src IS per-lane (swizzle goes there).
__device__ __forceinline__ void async_copy16(const bf16* g, bf16* l) {
    __builtin_amdgcn_global_load_lds(
        (const __attribute__((address_space(1))) u32*)g,
        (__attribute__((address_space(3))) u32*)l, 16, 0, 0);
}

#define SCALE 0.04508422002778f   // (1/sqrt(1024)) * log2(e), folded into Q

// ---------------------------------------------------------------------------
// Kernel 1: QKV projection + fused Wo fp32->bf16 (type 3). UNCHANGED.
// R12 diagnostic bound: proj < 67us (never surfaced over the 67us attn passes).
// ---------------------------------------------------------------------------
__global__ __launch_bounds__(256) void proj_kernel(
    const float* __restrict__ values, const float* __restrict__ keys,
    const float* __restrict__ query,  const float* __restrict__ Wv,
    const float* __restrict__ Wk,     const float* __restrict__ Wq,
    const float* __restrict__ Wo,
    bf16* __restrict__ qp, bf16* __restrict__ kp, bf16* __restrict__ vt,
    bf16* __restrict__ wb)
{
    const int t    = threadIdx.x;
    const int bh   = blockIdx.y;
    const int type = blockIdx.z;

    if (type == 3) {
        int idx = (bh * 16 + blockIdx.x) * 1024 + t * 4;
        f32x4 v = *(const f32x4*)(Wo + idx);
        *(bf16x4*)(wb + idx) = __builtin_convertvector(v, bf16x4);
        return;
    }

    const int b = bh >> 4, h = bh & 15;
    const int s0 = blockIdx.x * 128;
    const int w = t >> 6, lane = t & 63;
    const int m = lane & 15, g = lane >> 4;
    const int row0 = s0 + w * 32;

    const float* X = (type == 0) ? query : (type == 1) ? keys : values;
    const float* W = (type == 0) ? Wq    : (type == 1) ? Wk   : Wv;

    __shared__ bf16 Xs[128 * 72];   // staged X tile, bf16, padded stride

    // coalesced staging: 8 rounds x 256 thr x 16B fp32 = 32KB tile
    #pragma unroll
    for (int p = 0; p < 8; ++p) {
        int id = p * 256 + t;
        int row = id >> 4, cq = (id & 15) * 4;
        f32x4 v = *(const f32x4*)(X + (size_t)(b * S + s0 + row) * E + h * D + cq);
        if (type == 0) v *= SCALE;
        *(bf16x4*)(Xs + row * 72 + cq) = __builtin_convertvector(v, bf16x4);
    }

    bf16x8 wf[4][2];
    #pragma unroll
    for (int nt = 0; nt < 4; ++nt)
        #pragma unroll
        for (int kb = 0; kb < 2; ++kb) {
            const float* pw = W + (nt * 16 + m) * 64 + kb * 32 + g * 8;
            f32x4 lo = *(const f32x4*)pw;
            f32x4 hi = *(const f32x4*)(pw + 4);
            bf16x8 f;
            #pragma unroll
            for (int i = 0; i < 4; ++i) { f[i] = (bf16)lo[i]; f[4 + i] = (bf16)hi[i]; }
            wf[nt][kb] = f;
        }

    __syncthreads();

    bf16x8 xa[2][2];
    #pragma unroll
    for (int mt = 0; mt < 2; ++mt)
        #pragma unroll
        for (int kb = 0; kb < 2; ++kb)
            xa[mt][kb] = *(const bf16x8*)(Xs + (w * 32 + mt * 16 + m) * 72 + kb * 32 + g * 8);

    if (type == 2) {
        #pragma unroll
        for (int mt = 0; mt < 2; ++mt)
            #pragma unroll
            for (int nt = 0; nt < 4; ++nt) {
                f32x4 acc = (f32x4){0.f, 0.f, 0.f, 0.f};
                acc = mfma16(xa[mt][0], wf[nt][0], acc);
                acc = mfma16(xa[mt][1], wf[nt][1], acc);
                bf16x4 pk = __builtin_convertvector(acc, bf16x4);
                *(bf16x4*)(vt + (size_t)(bh * D + nt * 16 + m) * S + row0 + mt * 16 + g * 4) = pk;
            }
    } else {
        bf16* out = (type == 0) ? qp : kp;
        #pragma unroll
        for (int mt = 0; mt < 2; ++mt)
            #pragma unroll
            for (int nt = 0; nt < 4; ++nt) {
                f32x4 acc = (f32x4){0.f, 0.f, 0.f, 0.f};
                acc = mfma16(wf[nt][0], xa[mt][0], acc);
                acc = mfma16(wf[nt][1], xa[mt][1], acc);
                bf16x4 pk = __builtin_convertvector(acc, bf16x4);
                *(bf16x4*)(out + (size_t)(bh * S + row0 + mt * 16 + m) * D + nt * 16 + g * 4) = pk;
            }
    }
}

// ---------------------------------------------------------------------------
// Kernel 2: flash attention — R9 VERBATIM (best measured: 89.3us).
// R12 two-pass diagnostic reverted: split cost +45us (2x67 vs 89); its
// payoff was the bound proj/out_gemm < 67us each.
// ---------------------------------------------------------------------------
__global__ __launch_bounds__(256, 2) void attn_kernel(
    const bf16* __restrict__ qp, const bf16* __restrict__ kp,
    const bf16* __restrict__ vt, bf16* __restrict__ attn)
{
    const int t  = threadIdx.x;
    const int bh = blockIdx.x;
    const int b  = bh >> 4, h = bh & 15;
    const int q0 = blockIdx.y * 256;
    const int w  = t >> 6, lane = t & 63;
    const int l31 = lane & 31, h5 = lane >> 5;

    __shared__ bf16 Ks[2][64 * 64];   // [buf][row*64 + col], swizzled slots
    __shared__ bf16 Vs[2][64 * 64];

    // Q fragments: B operand, 2 q-blocks x 4 d-kblocks (held all kernel)
    bf16x8 qa[2][4];
    #pragma unroll
    for (int qb = 0; qb < 2; ++qb)
        #pragma unroll
        for (int kb = 0; kb < 4; ++kb)
            qa[qb][kb] = *(const bf16x8*)(qp + (size_t)(bh * S + q0 + w * 64 + qb * 32 + l31) * D + kb * 16 + h5 * 8);

    f32x16 O[2][2];                // [qb][db]
    #pragma unroll
    for (int qb = 0; qb < 2; ++qb)
        #pragma unroll
        for (int db = 0; db < 2; ++db)
            #pragma unroll
            for (int i = 0; i < 16; ++i) O[qb][db][i] = 0.f;
    float Lacc[2] = {0.f, 0.f};

    // staging geometry: 2 rounds x 256 thr x 16B = 8KB tile; per-lane source
    // row = p*32 + w*8 + (lane>>3); slot = (lane&7) ^ ((lane>>3)&7)
    const int srow  = lane >> 3;
    const int sslot = (lane & 7) ^ srow;
    const bf16* ks0 = kp + ((size_t)bh * S + w * 8 + srow) * D + sslot * 8;
    const bf16* vs0 = vt + ((size_t)bh * D + w * 8 + srow) * S + sslot * 8;
    const int swz = (l31 & 7);            // read-side XOR (row&7 == l31&7)

    // prologue: stage kt=0 into buf 0
    #pragma unroll
    for (int p = 0; p < 2; ++p) {
        async_copy16(ks0 + (size_t)(p * 32) * D, &Ks[0][p * 2048 + w * 512]);
        async_copy16(vs0 + (size_t)(p * 32) * S, &Vs[0][p * 2048 + w * 512]);
    }
    __syncthreads();

    int cur = 0;
    for (int kt = 0; kt < S / 64; ++kt) {
        if (kt + 1 < S / 64) {
            #pragma unroll
            for (int p = 0; p < 2; ++p) {
                async_copy16(ks0 + (size_t)(kt + 1) * 64 * D + (size_t)(p * 32) * D,
                             &Ks[cur ^ 1][p * 2048 + w * 512]);
                async_copy16(vs0 + (size_t)(p * 32) * S + (kt + 1) * 64,
                             &Vs[cur ^ 1][p * 2048 + w * 512]);
            }
        }
        const bf16* KsB = Ks[cur];
        const bf16* VsB = Vs[cur];

        #pragma unroll
        for (int kg = 0; kg < 2; ++kg) {
            bf16x8 kf[4];
            #pragma unroll
            for (int kb = 0; kb < 4; ++kb)
                kf[kb] = *(const bf16x8*)&KsB[(kg * 32 + l31) * 64 + (((kb * 2 + h5) ^ swz) << 3)];
            bf16x8 vf[2][2];   // [kap][db]
            #pragma unroll
            for (int kap = 0; kap < 2; ++kap)
                #pragma unroll
                for (int db = 0; db < 2; ++db)
                    vf[kap][db] = *(const bf16x8*)&VsB[(db * 32 + l31) * 64 + (((kg * 4 + kap * 2 + h5) ^ swz) << 3)];

            // ---- QK: E^T[key-slot][q] for 32 keys x 64 q ----
            f32x16 e[2];
            #pragma unroll
            for (int qb = 0; qb < 2; ++qb)
                #pragma unroll
                for (int i = 0; i < 16; ++i) e[qb][i] = 0.f;
            #pragma unroll
            for (int kb = 0; kb < 4; ++kb) {
                e[0] = mfma32(kf[kb], qa[0][kb], e[0]);
                e[1] = mfma32(kf[kb], qa[1][kb], e[1]);
            }

            // ---- exp2, pack, packed 4-shfl exchange (R5-derived), PV ----
            #pragma unroll
            for (int qb = 0; qb < 2; ++qb) {
                unsigned own[8];
                float ls = 0.f;
                #pragma unroll
                for (int c = 0; c < 8; ++c) {
                    float lo = __builtin_amdgcn_exp2f(e[qb][2 * c]);
                    float hi = __builtin_amdgcn_exp2f(e[qb][2 * c + 1]);
                    ls += lo + hi;
                    own[c] = pack2(lo, hi);
                }
                Lacc[qb] += ls;
                // packed exchange: one shfl serves both halves.
                unsigned x0 = __shfl_xor(h5 ? own[0] : own[2], 32, 64);
                unsigned x1 = __shfl_xor(h5 ? own[1] : own[3], 32, 64);
                unsigned x4 = __shfl_xor(h5 ? own[4] : own[6], 32, 64);
                unsigned x5 = __shfl_xor(h5 ? own[5] : own[7], 32, 64);
                {   // kap = 0
                    unsigned a0 = h5 ? x0 : own[0];
                    unsigned a1 = h5 ? x1 : own[1];
                    unsigned a2 = h5 ? own[2] : x0;
                    unsigned a3 = h5 ? own[3] : x1;
                    bf16x8 pf = frag4(a0, a1, a2, a3);
                    O[qb][0] = mfma32(pf, vf[0][0], O[qb][0]);
                    O[qb][1] = mfma32(pf, vf[0][1], O[qb][1]);
                }
                {   // kap = 1
                    unsigned a0 = h5 ? x4 : own[4];
                    unsigned a1 = h5 ? x5 : own[5];
                    unsigned a2 = h5 ? own[6] : x4;
                    unsigned a3 = h5 ? own[7] : x5;
                    bf16x8 pf = frag4(a0, a1, a2, a3);
                    O[qb][0] = mfma32(pf, vf[1][0], O[qb][0]);
                    O[qb][1] = mfma32(pf, vf[1][1], O[qb][1]);
                }
            }
        }
        __syncthreads();   // drains vmcnt: next tile's DMA complete; all waves done with cur
        cur ^= 1;
    }

    // ---- epilogue: L combine across halves, redistribute 1/L to O layout ----
    #pragma unroll
    for (int qb = 0; qb < 2; ++qb) {
        float Ls = Lacc[qb] + __shfl_xor(Lacc[qb], 32, 64);
        float li = 1.f / Ls;
        #pragma unroll
        for (int r = 0; r < 16; ++r) {
            int crow = (r & 3) + 8 * (r >> 2) + 4 * h5;
            float lr = __shfl(li, crow | (lane & 32), 64);
            int qg = q0 + w * 64 + qb * 32 + crow;
            #pragma unroll
            for (int db = 0; db < 2; ++db)
                attn[(size_t)(b * S + qg) * E + h * D + db * 32 + l31] =
                    (bf16)(O[qb][db][r] * lr);
        }
    }
}

// ---------------------------------------------------------------------------
// Kernel 3: out = attn @ Wo^T + bo — R13: GRID TRANSPOSE for XCD-local A reuse.
// Old grid (x=n:16, y=m:64): linear%8 = n%8 -> the 16 blocks sharing one
// 256KB A-slab scatter over all 8 XCDs -> A refetched per XCD ~ 128MB HBM.
// New grid (x=m:64, y=n:16): linear%8 = m%8 -> all 16 n-blocks of an A-slab
// land on ONE XCD -> A fetched once (16MB). Per-XCD set: 8 A-slabs (2MB) +
// full B (2MB) = 4MB = exactly one L2. Kernel body unchanged (R11-verified).
// ---------------------------------------------------------------------------
__global__ __launch_bounds__(256, 4) void out_gemm(
    const bf16* __restrict__ A, const bf16* __restrict__ wo,
    const float* __restrict__ bo, float* __restrict__ out)
{
    const int t  = threadIdx.x;
    const int m0 = blockIdx.x * 128;   // R13: m on x (fast dim)
    const int n0 = blockIdx.y * 64;    // R13: n on y
    const int w  = t >> 6, lane = t & 63;
    const int l31 = lane & 31, h5 = lane >> 5;
    const int wm = w >> 1, wn = w & 1;   // 2x2 waves over 128m x 64n

    __shared__ bf16 As[128 * 64];   // [m][k-slot], swizzled slots, 16KB
    __shared__ bf16 Bs[64 * 64];    // [n][k-slot], 8KB

    f32x16 acc[2];                  // [mi] : wave tile 64m x 32n
    #pragma unroll
    for (int mi = 0; mi < 2; ++mi)
        #pragma unroll
        for (int i = 0; i < 16; ++i) acc[mi][i] = 0.f;

    // staging source (swizzled): lane -> row = base + (lane>>3), slot = (lane&7)^(lane>>3)
    const int srow  = lane >> 3;
    const int sslot = (lane & 7) ^ srow;
    const bf16* asrc = A  + ((size_t)(m0 + w * 8 + srow)) * E + sslot * 8;
    const bf16* bsrc = wo + ((size_t)(n0 + w * 8 + srow)) * E + sslot * 8;
    const int swz = (l31 & 7);      // read-side XOR (row&7 == l31&7)

    for (int kt = 0; kt < E / 64; ++kt) {
        if (kt) __syncthreads();    // all waves done reading previous tile
        // DMA this K-slab: A 128x64 (4 rounds), B 64x64 (2 rounds)
        #pragma unroll
        for (int p = 0; p < 4; ++p)
            async_copy16(asrc + (size_t)(p * 32) * E + kt * 64, &As[(p * 32 + w * 8) * 64]);
        #pragma unroll
        for (int p = 0; p < 2; ++p)
            async_copy16(bsrc + (size_t)(p * 32) * E + kt * 64, &Bs[(p * 32 + w * 8) * 64]);
        __syncthreads();            // vmcnt drained -> tile ready

        #pragma unroll
        for (int ks = 0; ks < 4; ++ks) {
            bf16x8 bf = *(const bf16x8*)&Bs[(wn * 32 + l31) * 64 + (((ks * 2 + h5) ^ swz) << 3)];
            #pragma unroll
            for (int mi = 0; mi < 2; ++mi) {
                bf16x8 af = *(const bf16x8*)&As[(wm * 64 + mi * 32 + l31) * 64 + (((ks * 2 + h5) ^ swz) << 3)];
                acc[mi] = mfma32(af, bf, acc[mi]);
            }
        }
    }

    // epilogue: D col = l31 (n), row = (r&3)+8*(r>>2)+4*h5 (m); bias along n
    const float bias = bo[n0 + wn * 32 + l31];
    #pragma unroll
    for (int mi = 0; mi < 2; ++mi)
        #pragma unroll
        for (int r = 0; r < 16; ++r) {
            int crow = (r & 3) + 8 * (r >> 2) + 4 * h5;
            out[(size_t)(m0 + wm * 64 + mi * 32 + crow) * E + n0 + wn * 32 + l31] =
                acc[mi][r] + bias;
        }
}

// ---------------------------------------------------------------------------
extern "C" void kernel_launch(void* const* d_in, const int* in_sizes, int n_in,
                              void* d_out, int out_size, void* d_ws, size_t ws_size,
                              hipStream_t stream) {
    const float* values = (const float*)d_in[0];
    const float* keys   = (const float*)d_in[1];
    const float* query  = (const float*)d_in[2];
    const float* Wv     = (const float*)d_in[3];
    const float* Wk     = (const float*)d_in[4];
    const float* Wq     = (const float*)d_in[5];
    const float* Wo     = (const float*)d_in[6];
    const float* bo     = (const float*)d_in[7];
    float* out = (float*)d_out;

    bf16* qp   = (bf16*)d_ws;
    bf16* kp   = qp  + (size_t)BH * S * D;
    bf16* vt   = kp  + (size_t)BH * S * D;
    bf16* attn = vt  + (size_t)BH * S * D;
    bf16* wb   = attn + (size_t)BH * S * D;   // 2 MB for bf16 Wo

    proj_kernel<<<dim3(S / 128, BH, 4), 256, 0, stream>>>(
        values, keys, query, Wv, Wk, Wq, Wo, qp, kp, vt, wb);
    attn_kernel<<<dim3(BH, S / 256), 256, 0, stream>>>(qp, kp, vt, attn);
    out_gemm<<<dim3((B * S) / 128, E / 64), 256, 0, stream>>>(attn, wb, bo, out);
}